// Round 1
// baseline (5759.998 us; speedup 1.0000x reference)
//
#include <hip/hip_runtime.h>
#include <math.h>

#define DEV __device__ __forceinline__

constexpr int Bn  = 4;
constexpr int C64 = 64;
constexpr int L   = 4096;     // 64*64
constexpr int HID = 170;
constexpr int DIN = 340;
constexpr int NST = 16;
constexpr int DTR = 11;
constexpr int KD  = 4;
constexpr int XD  = 43;       // DTR + 2*NST
constexpr int XDP = 44;       // padded stride

// ---- workspace layout (floats) ----
constexpr size_t o_rn   = 0;                       // B*L*64   (pixel-major)
constexpr size_t o_sn   = o_rn  + (size_t)Bn*L*C64;
constexpr size_t o_pre  = o_sn  + (size_t)Bn*L*C64;        // B*L*192 pixel-major
constexpr size_t o_xcv  = 0;                       // phase2: xconvT B*L*340 pixel-major (reuses rn/sn/pre)
constexpr size_t regA_end = (size_t)Bn*L*DIN;              // 5,570,560
constexpr size_t o_qkv  = regA_end;                        // B*192*L channel-major
constexpr size_t o_xdbl = regA_end;                        // phase2: B*K*L*44
constexpr size_t regB_end = o_qkv + (size_t)Bn*192*L;      // 8,716,288
constexpr size_t o_inv  = regB_end;                        // 512
constexpr size_t o_attn = o_inv + 512;                     // 8192
constexpr size_t o_aout = o_attn + 8192;                   // B*L*64 pixel-major
constexpr size_t o_r    = o_aout + (size_t)Bn*L*C64;       // channel-major
constexpr size_t o_ln2  = o_r    + (size_t)Bn*L*C64;       // pixel-major
constexpr size_t o_xpre = o_ln2  + (size_t)Bn*L*C64;       // B*340*L channel-major
constexpr size_t o_yc   = o_xpre;                          // phase2: ycomb B*L*340 pixel-major (then t in-place)
constexpr size_t o_xd   = o_xpre + (size_t)Bn*DIN*L;       // channel-major
constexpr size_t o_r2   = o_xd   + (size_t)Bn*DIN*L;       // B*L*170 pixel-major
constexpr size_t o_sso  = o_r2;                            // phase2: B*L*170 pixel-major
constexpr size_t o_xxz  = o_r2   + (size_t)Bn*L*HID;       // B*L*680 pixel-major
constexpr size_t o_x2t  = o_xxz  + (size_t)Bn*L*680;       // B*L*170 pixel-major
constexpr size_t WS_FLOATS = o_x2t + (size_t)Bn*L*HID;     // ~158.9 MB

DEV float wred_sum(float v){
  #pragma unroll
  for(int s=32;s>0;s>>=1) v += __shfl_xor(v, s, 64);
  return v;
}

DEV int pmap(int k, int l){
  switch(k){
    case 0:  return l;
    case 1:  return ((l&63)<<6) | (l>>6);
    case 2:  return 4095 - l;
    default: { int t = 4095 - l; return ((t&63)<<6) | (t>>6); }
  }
}

// 1) s = conv1(upsample(S)); r_n = LN_cf(R); s_n = LN_cf(s)   [64 thr = one pixel]
__global__ __launch_bounds__(64) void k_upln(const float* R, const float* S,
    const float* w1, const float* b1, const float* nw, const float* nb,
    float* rn, float* sn){
  int blk = blockIdx.x;            // b*L+p
  int b = blk >> 12, p = blk & 4095;
  int y = p >> 6, x = p & 63;
  int c = threadIdx.x;
  const float* Sp = S + (size_t)b*32*1024 + (size_t)(y>>1)*32 + (x>>1);
  const float* wr = w1 + c*32;
  float sv = b1[c];
  #pragma unroll
  for(int ci=0; ci<32; ci++) sv += Sp[(size_t)ci*1024] * wr[ci];
  float rv = R[((size_t)b*C64 + c)*L + p];
  float mr = wred_sum(rv) * (1.f/64.f);
  float ms = wred_sum(sv) * (1.f/64.f);
  float dr = rv - mr, dsv = sv - ms;
  float vr = wred_sum(dr*dr) * (1.f/64.f);
  float vs = wred_sum(dsv*dsv) * (1.f/64.f);
  float g = nw[c], be = nb[c];
  rn[(size_t)blk*C64 + c] = dr  * rsqrtf(vr + 1e-6f) * g + be;
  sn[(size_t)blk*C64 + c] = dsv * rsqrtf(vs + 1e-6f) * g + be;
}

// 2) pre[0:64]=q_w@rn ; pre[64:192]=kv_w@sn     [192 thr per pixel]
__global__ __launch_bounds__(192) void k_qkvproj(const float* rn, const float* sn,
    const float* qw, const float* kvw, float* pre){
  __shared__ float sr[64], ss[64];
  int blk = blockIdx.x; int tid = threadIdx.x;
  if(tid < 64) sr[tid] = rn[(size_t)blk*64 + tid];
  else if(tid < 128) ss[tid-64] = sn[(size_t)blk*64 + (tid-64)];
  __syncthreads();
  float acc = 0.f;
  if(tid < 64){
    const float* w = qw + tid*64;
    #pragma unroll 8
    for(int i=0;i<64;i++) acc += w[i]*sr[i];
  } else {
    const float* w = kvw + (size_t)(tid-64)*64;
    #pragma unroll 8
    for(int i=0;i<64;i++) acc += w[i]*ss[i];
  }
  pre[(size_t)blk*192 + tid] = acc;
}

// 3) depthwise 3x3 on pre -> qkv (channel-major)
__global__ __launch_bounds__(192) void k_dwqkv(const float* pre, const float* qdw,
    const float* kvdw, float* qkv){
  int blk = blockIdx.x; int b = blk>>12, p = blk&4095;
  int y = p>>6, x = p&63;
  int cc = threadIdx.x;
  const float* w = (cc<64) ? (qdw + cc*9) : (kvdw + (size_t)(cc-64)*9);
  float acc = 0.f;
  #pragma unroll
  for(int ky=0;ky<3;ky++){ int yy=y+ky-1; if((unsigned)yy>=64u) continue;
    #pragma unroll
    for(int kx=0;kx<3;kx++){ int xx=x+kx-1; if((unsigned)xx>=64u) continue;
      acc += pre[((size_t)(b<<12) + (yy<<6)+xx)*192 + cc] * w[ky*3+kx]; } }
  qkv[((size_t)b*192+cc)*L + p] = acc;
}

// 4) inverse L2 norms of q,k rows
__global__ __launch_bounds__(256) void k_rownorm(const float* qkv, float* inv){
  int row = blockIdx.x; int b = row>>7, cc = row&127;
  const float* src = qkv + ((size_t)b*192 + cc)*L;
  float s = 0.f;
  for(int i=threadIdx.x; i<L; i+=256){ float v = src[i]; s += v*v; }
  __shared__ float red[256];
  red[threadIdx.x] = s; __syncthreads();
  for(int st=128; st>0; st>>=1){ if(threadIdx.x<st) red[threadIdx.x]+=red[threadIdx.x+st]; __syncthreads(); }
  if(threadIdx.x==0) inv[row] = 1.f / fmaxf(sqrtf(red[0]), 1e-12f);
}

// 5) Gram G[c,d] = sum_l q[c,l] k[d,l]   (one block per (b,h))
__global__ __launch_bounds__(1024) void k_gram(const float* qkv, float* G){
  int bh = blockIdx.x; int b = bh>>1, h = bh&1;
  __shared__ float qt[32][129], kt[32][129];
  int tid = threadIdx.x;
  int c = tid>>5, d = tid&31;
  const float* qbase = qkv + ((size_t)b*192 + h*32)*L;
  const float* kbase = qkv + ((size_t)b*192 + 64 + h*32)*L;
  float acc = 0.f;
  for(int t0=0;t0<L;t0+=128){
    __syncthreads();
    for(int e=tid; e<4096; e+=1024){ int cr=e>>7, li=e&127;
      qt[cr][li] = qbase[(size_t)cr*L + t0 + li];
      kt[cr][li] = kbase[(size_t)cr*L + t0 + li]; }
    __syncthreads();
    #pragma unroll 8
    for(int li=0; li<128; li++) acc += qt[c][li]*kt[d][li];
  }
  G[((size_t)bh*32 + c)*32 + d] = acc;
}

// 6) softmax rows (normalize by L2 norms, scale by temperature)  [1 block]
__global__ __launch_bounds__(256) void k_softmax(float* G, const float* inv, const float* temp){
  int row = threadIdx.x;            // (b*2+h)*32+c
  int b = row>>6, h = (row>>5)&1, c = row&31;
  float* g = G + (size_t)row*32;
  float iq = inv[b*128 + h*32 + c];
  float tp = temp[h];
  float vals[32]; float m = -1e30f;
  #pragma unroll
  for(int d=0; d<32; d++){ float v = g[d]*iq*inv[b*128+64+h*32+d]*tp; vals[d]=v; m = fmaxf(m,v); }
  float s = 0.f;
  #pragma unroll
  for(int d=0; d<32; d++){ vals[d] = __expf(vals[d]-m); s += vals[d]; }
  float r = 1.f/s;
  #pragma unroll
  for(int d=0; d<32; d++) g[d] = vals[d]*r;
}

// 7) out[c,l] = sum_d attn[c,d] v[d,l]  -> aout pixel-major
__global__ __launch_bounds__(256) void k_attnout(const float* G, const float* qkv, float* aout){
  int blk = blockIdx.x;            // (b*2+h)*64 + lt
  int lt = blk & 63; int bh = blk >> 6; int b = bh>>1, h = bh&1;
  __shared__ float at[32][32];
  __shared__ float vt[32][65];
  int tid = threadIdx.x;
  for(int e=tid; e<1024; e+=256) ((float*)at)[e] = G[(size_t)bh*1024 + e];
  const float* vbase = qkv + ((size_t)b*192 + 128 + h*32)*L + lt*64;
  for(int e=tid; e<2048; e+=256){ int d=e>>6, li=e&63; vt[d][li] = vbase[(size_t)d*L + li]; }
  __syncthreads();
  int li = tid & 63; int c0 = tid >> 6;
  int p = lt*64 + li;
  for(int cc=c0; cc<32; cc+=4){
    float acc = 0.f;
    #pragma unroll
    for(int d=0; d<32; d++) acc += at[cc][d]*vt[d][li];
    aout[((size_t)(b<<12) + p)*64 + h*32 + cc] = acc;
  }
}

// 8) r = R + proj @ aout     (channel-major out)
__global__ __launch_bounds__(64) void k_projadd(const float* aout, const float* pw,
    const float* R, float* r){
  int blk = blockIdx.x; int b = blk>>12, p = blk&4095;
  int oc = threadIdx.x;
  __shared__ float s[64];
  s[oc] = aout[(size_t)blk*64 + oc];
  __syncthreads();
  float acc = R[((size_t)b*64+oc)*L + p];
  const float* w = pw + oc*64;
  #pragma unroll 8
  for(int i=0;i<64;i++) acc += w[i]*s[i];
  r[((size_t)b*64+oc)*L + p] = acc;
}

// 9) ln2 = LN_cf(r)  (pixel-major out)
__global__ __launch_bounds__(64) void k_ln2(const float* r, const float* nw, const float* nb, float* ln2){
  int blk = blockIdx.x; int b = blk>>12, p = blk&4095;
  int c = threadIdx.x;
  float v = r[((size_t)b*64+c)*L + p];
  float m = wred_sum(v)*(1.f/64.f);
  float d = v - m;
  float var = wred_sum(d*d)*(1.f/64.f);
  ln2[(size_t)blk*64 + c] = d*rsqrtf(var+1e-6f)*nw[c] + nb[c];
}

// 10) xpre = pin_w @ ln2  (64->340), 4-pixel tile, channel-major out
__global__ __launch_bounds__(384) void k_pin(const float* ln2, const float* pw, float* xpre){
  int blk = blockIdx.x;                 // Bn*1024
  int b = blk >> 10; int p0 = (blk & 1023)*4;
  __shared__ float s[4][64];
  int tid = threadIdx.x;
  if(tid < 256) s[tid>>6][tid&63] = ln2[((size_t)(b<<12)+p0+(tid>>6))*64 + (tid&63)];
  __syncthreads();
  if(tid < DIN){
    const float* w = pw + (size_t)tid*64;
    float a0=0,a1=0,a2=0,a3=0;
    #pragma unroll 8
    for(int i=0;i<64;i++){ float wv=w[i]; a0+=wv*s[0][i]; a1+=wv*s[1][i]; a2+=wv*s[2][i]; a3+=wv*s[3][i]; }
    size_t base = ((size_t)b*DIN + tid)*L + p0;
    xpre[base]=a0; xpre[base+1]=a1; xpre[base+2]=a2; xpre[base+3]=a3;
  }
}

// 11) generic depthwise 3x3, channel-major -> channel-major
__global__ __launch_bounds__(256) void k_dw_cm(const float* in, const float* w9, float* out, int nch){
  int blk = blockIdx.x;
  int pt = blk & 15; int row = blk >> 4;     // row = b*nch + c
  int c = row % nch;
  const float* w = w9 + (size_t)c*9;
  int p = pt*256 + threadIdx.x;
  int y = p>>6, x = p&63;
  const float* base = in + (size_t)row*L;
  float acc = 0.f;
  #pragma unroll
  for(int ky=0;ky<3;ky++){ int yy=y+ky-1; if((unsigned)yy>=64u) continue;
    #pragma unroll
    for(int kx=0;kx<3;kx++){ int xx=x+kx-1; if((unsigned)xx>=64u) continue;
      acc += base[(yy<<6)+xx]*w[ky*3+kx]; } }
  out[(size_t)row*L + p] = acc;
}

// 12) r2 = LN_last(x1) over 170 ch (ln1, eps 1e-6), pixel-major out
__global__ __launch_bounds__(256) void k_ln1(const float* xd, const float* w, const float* bb, float* r2){
  int blk = blockIdx.x; int b = blk>>12, p = blk&4095;
  int tid = threadIdx.x;
  __shared__ float red[256]; __shared__ float smu, siv;
  float v = (tid<HID) ? xd[((size_t)b*DIN + tid)*L + p] : 0.f;
  red[tid] = v; __syncthreads();
  for(int st=128;st>0;st>>=1){ if(tid<st) red[tid]+=red[tid+st]; __syncthreads(); }
  if(tid==0) smu = red[0]*(1.f/HID);
  __syncthreads();
  float d = (tid<HID) ? v - smu : 0.f;
  red[tid] = d*d; __syncthreads();
  for(int st=128;st>0;st>>=1){ if(tid<st) red[tid]+=red[tid+st]; __syncthreads(); }
  if(tid==0) siv = rsqrtf(red[0]*(1.f/HID) + 1e-6f);
  __syncthreads();
  if(tid<HID) r2[(size_t)blk*HID + tid] = d*siv*w[tid] + bb[tid];
}

// 13) xxz = r2 @ in_w.T (170->680), 8-pixel tile, pixel-major out
__global__ __launch_bounds__(704) void k_inproj(const float* r2, const float* inw, float* xxz){
  int blk = blockIdx.x;                 // Bn*512
  int b = blk >> 9; int p0 = (blk & 511)*8;
  __shared__ float s[8][HID];
  int tid = threadIdx.x;
  for(int e=tid; e<8*HID; e+=704){ int px=e/HID, i=e-px*HID;
    s[px][i] = r2[((size_t)(b<<12)+p0+px)*HID + i]; }
  __syncthreads();
  if(tid < 680){
    const float* w = inw + (size_t)tid*HID;
    float acc[8] = {0,0,0,0,0,0,0,0};
    for(int i=0;i<HID;i++){ float wv = w[i];
      #pragma unroll
      for(int j=0;j<8;j++) acc[j] += wv*s[j][i]; }
    #pragma unroll
    for(int j=0;j<8;j++) xxz[((size_t)(b<<12)+p0+j)*680 + tid] = acc[j];
  }
}

// 14) xconvT = silu(dw3x3(xx)+bias), pixel-major out
__global__ __launch_bounds__(384) void k_dwss(const float* xxz, const float* w9,
    const float* bias, float* xcv){
  int blk = blockIdx.x; int b = blk>>12, p = blk&4095;
  int y = p>>6, x = p&63;
  int c = threadIdx.x;
  if(c < DIN){
    const float* w = w9 + (size_t)c*9;
    float acc = bias[c];
    #pragma unroll
    for(int ky=0;ky<3;ky++){ int yy=y+ky-1; if((unsigned)yy>=64u) continue;
      #pragma unroll
      for(int kx=0;kx<3;kx++){ int xx=x+kx-1; if((unsigned)xx>=64u) continue;
        acc += xxz[((size_t)(b<<12)+(yy<<6)+xx)*680 + c]*w[ky*3+kx]; } }
    xcv[(size_t)blk*DIN + c] = acc/(1.f+__expf(-acc));
  }
}

// 15) xdbl[b,k,l,0:43] = xpw[k] @ xs[b,k,:,l]   (8 l's per block)
__global__ __launch_bounds__(384) void k_xdbl(const float* xcv, const float* xpw, float* xdbl){
  int blk = blockIdx.x;                 // Bn*KD*512
  int lt = blk & 511; int bk = blk >> 9; int b = bk >> 2, k = bk & 3;
  __shared__ float s[8][DIN];
  int tid = threadIdx.x;
  int l0 = lt*8;
  for(int e=tid; e<8*DIN; e+=384){ int ls=e/DIN, d=e-ls*DIN;
    s[ls][d] = xcv[((size_t)(b<<12) + pmap(k, l0+ls))*DIN + d]; }
  __syncthreads();
  if(tid < 8*XD){ int ls = tid/XD, cc = tid - ls*XD;
    const float* w = xpw + ((size_t)k*XD + cc)*DIN;
    float acc = 0.f;
    for(int d=0; d<DIN; d++) acc += w[d]*s[ls][d];
    xdbl[((size_t)bk*L + l0+ls)*XDP + cc] = acc; }
}

// 16) selective scan; atomicAdd into ycomb at the source pixel
__global__ __launch_bounds__(64) void k_scan(const float* xcv, const float* xdbl,
    const float* dtw, const float* dtb, const float* Alog, const float* Dss, float* yc){
  int blk = blockIdx.x;                 // 16*6
  int chunk = blk % 6; int bk = blk / 6; int b = bk>>2, k = bk&3;
  int d = chunk*64 + threadIdx.x;
  bool act = d < DIN;
  int kd = k*DIN + (act ? d : 0);
  float A[NST], h[NST], wdt[DTR];
  float dtbv = 0.f, Dv = 0.f;
  #pragma unroll
  for(int n=0;n<NST;n++){ h[n] = 0.f; A[n] = 0.f; }
  #pragma unroll
  for(int r=0;r<DTR;r++) wdt[r] = 0.f;
  if(act){
    #pragma unroll
    for(int n=0;n<NST;n++) A[n] = -__expf(Alog[(size_t)kd*NST + n]);
    #pragma unroll
    for(int r=0;r<DTR;r++) wdt[r] = dtw[(size_t)kd*DTR + r];
    dtbv = dtb[kd]; Dv = Dss[kd];
  }
  __shared__ float row[8*XDP];
  const float* xrow = xdbl + (size_t)bk*L*XDP;
  const float* xc   = xcv + (size_t)(b<<12)*DIN;
  float* ycb = yc + (size_t)(b<<12)*DIN;
  for(int l0=0; l0<L; l0+=8){
    __syncthreads();
    for(int e=threadIdx.x; e<8*XDP; e+=64) row[e] = xrow[(size_t)l0*XDP + e];
    __syncthreads();
    for(int ls=0; ls<8; ls++){
      int l = l0 + ls;
      const float* rw = &row[ls*XDP];
      float dt = dtbv;
      #pragma unroll
      for(int rr=0;rr<DTR;rr++) dt += wdt[rr]*rw[rr];
      dt = (dt > 20.f) ? dt : log1pf(__expf(dt));
      int p = pmap(k, l);
      float u = act ? xc[(size_t)p*DIN + d] : 0.f;
      float du = dt*u;
      float yv = Dv*u;
      #pragma unroll
      for(int n=0;n<NST;n++){
        float e_ = __expf(A[n]*dt);
        h[n] = e_*h[n] + du*rw[DTR+n];
        yv += h[n]*rw[DTR+NST+n];
      }
      if(act) atomicAdd(&ycb[(size_t)p*DIN + d], yv);
    }
  }
}

// 17) x2t = tanh(dw3x3(x2)) + x2   (pixel-major out)
__global__ __launch_bounds__(256) void k_x2t(const float* xd, const float* w9, float* x2t){
  int blk = blockIdx.x;
  int pt = blk & 15; int g = blk >> 4;       // g = b*HID + c
  int b = g / HID, c = g - b*HID;
  int p = pt*256 + threadIdx.x;
  int y = p>>6, x = p&63;
  const float* base = xd + ((size_t)b*DIN + HID + c)*L;
  const float* w = w9 + (size_t)c*9;
  float acc = 0.f;
  #pragma unroll
  for(int ky=0;ky<3;ky++){ int yy=y+ky-1; if((unsigned)yy>=64u) continue;
    #pragma unroll
    for(int kx=0;kx<3;kx++){ int xx=x+kx-1; if((unsigned)xx>=64u) continue;
      acc += base[(yy<<6)+xx]*w[ky*3+kx]; } }
  x2t[((size_t)(b<<12)+p)*HID + c] = tanhf(acc) + base[p];
}

// 18) t = LN(y; onorm, eps 1e-5) * silu(z)   -- in place over ycomb
__global__ __launch_bounds__(256) void k_yln(float* yc, const float* xxz,
    const float* ow, const float* ob){
  int blk = blockIdx.x; int tid = threadIdx.x;
  __shared__ float yv[DIN]; __shared__ float red[256]; __shared__ float smu, siv;
  float* dst = yc + (size_t)blk*DIN;
  float s = 0.f;
  for(int i=tid;i<DIN;i+=256){ float v = dst[i]; yv[i] = v; s += v; }
  red[tid] = s; __syncthreads();
  for(int st=128;st>0;st>>=1){ if(tid<st) red[tid]+=red[tid+st]; __syncthreads(); }
  if(tid==0) smu = red[0]*(1.f/DIN);
  __syncthreads();
  s = 0.f;
  for(int i=tid;i<DIN;i+=256){ float d = yv[i]-smu; s += d*d; }
  red[tid] = s; __syncthreads();
  for(int st=128;st>0;st>>=1){ if(tid<st) red[tid]+=red[tid+st]; __syncthreads(); }
  if(tid==0) siv = rsqrtf(red[0]*(1.f/DIN) + 1e-5f);
  __syncthreads();
  const float* zp = xxz + (size_t)blk*680 + DIN;
  for(int i=tid;i<DIN;i+=256){
    float zz = zp[i];
    float lnv = (yv[i]-smu)*siv*ow[i] + ob[i];
    dst[i] = lnv * (zz/(1.f+__expf(-zz)));
  }
}

// 19) sso = t @ outw.T (340->170), 8-pixel tile, pixel-major out
__global__ __launch_bounds__(256) void k_outproj(const float* t, const float* ow, float* sso){
  int blk = blockIdx.x;                 // Bn*512
  int b = blk >> 9; int p0 = (blk & 511)*8;
  __shared__ float s[8][DIN];
  int tid = threadIdx.x;
  for(int e=tid; e<8*DIN; e+=256){ int px=e/DIN, i=e-px*DIN;
    s[px][i] = t[((size_t)(b<<12)+p0+px)*DIN + i]; }
  __syncthreads();
  if(tid < HID){
    const float* w = ow + (size_t)tid*DIN;
    float acc[8] = {0,0,0,0,0,0,0,0};
    for(int i=0;i<DIN;i++){ float wv = w[i];
      #pragma unroll
      for(int j=0;j<8;j++) acc[j] += wv*s[j][i]; }
    #pragma unroll
    for(int j=0;j<8;j++) sso[((size_t)(b<<12)+p0+j)*HID + tid] = acc[j];
  }
}

// 20) out = r + pout_w @ ((tanh(sso)+x1) * x2t)    (4-pixel tile)
__global__ __launch_bounds__(256) void k_final(const float* sso, const float* xd,
    const float* x2t, const float* pw, const float* r, float* out){
  int blk = blockIdx.x;                 // Bn*1024
  int b = blk >> 10; int p0 = (blk & 1023)*4;
  __shared__ float m[4][HID];
  int tid = threadIdx.x;
  for(int e=tid; e<4*HID; e+=256){ int px=e/HID, cc=e-px*HID;
    int p = p0 + px;
    float x1 = xd[((size_t)b*DIN + cc)*L + p];
    float s1 = tanhf(sso[((size_t)(b<<12)+p)*HID + cc]) + x1;
    m[px][cc] = s1 * x2t[((size_t)(b<<12)+p)*HID + cc];
  }
  __syncthreads();
  int oc = tid & 63, px = tid >> 6;
  const float* w = pw + (size_t)oc*HID;
  float acc = r[((size_t)b*64+oc)*L + p0+px];
  for(int i=0;i<HID;i++) acc += w[i]*m[px][i];
  out[((size_t)b*64+oc)*L + p0+px] = acc;
}

extern "C" void kernel_launch(void* const* d_in, const int* in_sizes, int n_in,
                              void* d_out, int out_size, void* d_ws, size_t ws_size,
                              hipStream_t stream) {
  const float* R     = (const float*)d_in[0];
  const float* S     = (const float*)d_in[1];
  const float* c1w   = (const float*)d_in[2];
  const float* c1b   = (const float*)d_in[3];
  const float* n1w   = (const float*)d_in[4];
  const float* n1b   = (const float*)d_in[5];
  const float* n2w   = (const float*)d_in[6];
  const float* n2b   = (const float*)d_in[7];
  const float* temp  = (const float*)d_in[8];
  const float* qw    = (const float*)d_in[9];
  const float* qdw   = (const float*)d_in[10];
  const float* kvw   = (const float*)d_in[11];
  const float* kvdw  = (const float*)d_in[12];
  const float* pjw   = (const float*)d_in[13];
  const float* pinw  = (const float*)d_in[14];
  const float* dww   = (const float*)d_in[15];
  const float* dw2w  = (const float*)d_in[16];
  const float* poutw = (const float*)d_in[17];
  const float* ln1w  = (const float*)d_in[18];
  const float* ln1b  = (const float*)d_in[19];
  const float* inw   = (const float*)d_in[20];
  const float* scw   = (const float*)d_in[21];
  const float* scb   = (const float*)d_in[22];
  const float* xpw   = (const float*)d_in[23];
  const float* dtw   = (const float*)d_in[24];
  const float* dtb   = (const float*)d_in[25];
  const float* Alog  = (const float*)d_in[26];
  const float* Dss   = (const float*)d_in[27];
  const float* onw   = (const float*)d_in[28];
  const float* onb   = (const float*)d_in[29];
  const float* outw  = (const float*)d_in[30];
  float* ws  = (float*)d_ws;
  float* out = (float*)d_out;

  float* rn   = ws + o_rn;
  float* sn   = ws + o_sn;
  float* pre  = ws + o_pre;
  float* qkv  = ws + o_qkv;
  float* inv  = ws + o_inv;
  float* attn = ws + o_attn;
  float* aout = ws + o_aout;
  float* r    = ws + o_r;
  float* ln2  = ws + o_ln2;
  float* xpre = ws + o_xpre;
  float* xd   = ws + o_xd;
  float* r2   = ws + o_r2;
  float* xxz  = ws + o_xxz;
  float* xcv  = ws + o_xcv;
  float* xdbl = ws + o_xdbl;
  float* yc   = ws + o_yc;
  float* sso  = ws + o_sso;
  float* x2t  = ws + o_x2t;

  // attention branch
  k_upln   <<<Bn*L, 64, 0, stream>>>(R, S, c1w, c1b, n1w, n1b, rn, sn);
  k_qkvproj<<<Bn*L, 192, 0, stream>>>(rn, sn, qw, kvw, pre);
  k_dwqkv  <<<Bn*L, 192, 0, stream>>>(pre, qdw, kvdw, qkv);
  k_rownorm<<<Bn*128, 256, 0, stream>>>(qkv, inv);
  k_gram   <<<Bn*2, 1024, 0, stream>>>(qkv, attn);
  k_softmax<<<1, 256, 0, stream>>>(attn, inv, temp);
  k_attnout<<<Bn*2*64, 256, 0, stream>>>(attn, qkv, aout);
  k_projadd<<<Bn*L, 64, 0, stream>>>(aout, pjw, R, r);
  // IEL branch
  k_ln2    <<<Bn*L, 64, 0, stream>>>(r, n2w, n2b, ln2);
  k_pin    <<<Bn*(L/4), 384, 0, stream>>>(ln2, pinw, xpre);
  k_dw_cm  <<<Bn*DIN*16, 256, 0, stream>>>(xpre, dww, xd, DIN);
  k_ln1    <<<Bn*L, 256, 0, stream>>>(xd, ln1w, ln1b, r2);
  // SS2D
  k_inproj <<<Bn*(L/8), 704, 0, stream>>>(r2, inw, xxz);
  k_dwss   <<<Bn*L, 384, 0, stream>>>(xxz, scw, scb, xcv);
  k_xdbl   <<<Bn*KD*(L/8), 384, 0, stream>>>(xcv, xpw, xdbl);
  hipMemsetAsync(yc, 0, (size_t)Bn*L*DIN*sizeof(float), stream);
  k_scan   <<<16*6, 64, 0, stream>>>(xcv, xdbl, dtw, dtb, Alog, Dss, yc);
  k_x2t    <<<Bn*HID*16, 256, 0, stream>>>(xd, dw2w, x2t);
  k_yln    <<<Bn*L, 256, 0, stream>>>(yc, xxz, onw, onb);
  k_outproj<<<Bn*(L/8), 256, 0, stream>>>(yc, outw, sso);
  k_final  <<<Bn*(L/4), 256, 0, stream>>>(sso, xd, x2t, poutw, r, out);
}

// Round 2
// 1507.329 us; speedup vs baseline: 3.8213x; 3.8213x over previous
//
#include <hip/hip_runtime.h>
#include <math.h>

#define DEV __device__ __forceinline__

constexpr int Bn  = 4;
constexpr int C64 = 64;
constexpr int L   = 4096;     // 64*64
constexpr int HID = 170;
constexpr int DIN = 340;
constexpr int NST = 16;
constexpr int DTR = 11;
constexpr int KD  = 4;
constexpr int XD  = 43;       // DTR + 2*NST
constexpr int XDP = 44;       // padded stride
constexpr int NCH = 32;       // scan chunks
constexpr int CLEN = L / NCH; // 128 steps per chunk

// ---- workspace layout (floats) ----
constexpr size_t o_rn   = 0;                       // B*L*64   (pixel-major)
constexpr size_t o_sn   = o_rn  + (size_t)Bn*L*C64;
constexpr size_t o_pre  = o_sn  + (size_t)Bn*L*C64;        // B*L*192 pixel-major
constexpr size_t o_xcv  = 0;                       // phase2: xconvT B*L*340 pixel-major (reuses rn/sn/pre)
constexpr size_t regA_end = (size_t)Bn*L*DIN;              // 5,570,560
constexpr size_t o_qkv  = regA_end;                        // B*192*L channel-major
constexpr size_t o_xdbl = regA_end;                        // phase2: B*K*L*44
constexpr size_t regB_end = o_qkv + (size_t)Bn*192*L;      // 8,716,288
constexpr size_t o_inv  = regB_end;                        // 512
constexpr size_t o_attn = o_inv + 512;                     // 8192
constexpr size_t o_aout = o_attn + 8192;                   // B*L*64 pixel-major
constexpr size_t o_r    = o_aout + (size_t)Bn*L*C64;       // channel-major
constexpr size_t o_ln2  = o_r    + (size_t)Bn*L*C64;       // pixel-major; phase2: sdt (16*32*340)
constexpr size_t o_xpre = o_ln2  + (size_t)Bn*L*C64;       // B*340*L channel-major
constexpr size_t o_yc   = o_xpre;                          // phase2: ycomb B*L*340 pixel-major (then t in-place)
constexpr size_t o_xd   = o_xpre + (size_t)Bn*DIN*L;       // channel-major
constexpr size_t o_r2   = o_xd   + (size_t)Bn*DIN*L;       // B*L*170 pixel-major; phase2: hend/hin (16*32*16*340 = exact fit)
constexpr size_t o_sso  = o_r2;                            // phase3: B*L*170 pixel-major
constexpr size_t o_xxz  = o_r2   + (size_t)Bn*L*HID;       // B*L*680 pixel-major
constexpr size_t o_x2t  = o_xxz  + (size_t)Bn*L*680;       // B*L*170 pixel-major
constexpr size_t WS_FLOATS = o_x2t + (size_t)Bn*L*HID;     // ~158.9 MB

DEV float wred_sum(float v){
  #pragma unroll
  for(int s=32;s>0;s>>=1) v += __shfl_xor(v, s, 64);
  return v;
}

DEV int pmap(int k, int l){
  switch(k){
    case 0:  return l;
    case 1:  return ((l&63)<<6) | (l>>6);
    case 2:  return 4095 - l;
    default: { int t = 4095 - l; return ((t&63)<<6) | (t>>6); }
  }
}

DEV float softplus_f(float x){
  return (x > 20.f) ? x : __logf(1.f + __expf(x));
}

// 1) s = conv1(upsample(S)); r_n = LN_cf(R); s_n = LN_cf(s)   [64 thr = one pixel]
__global__ __launch_bounds__(64) void k_upln(const float* R, const float* S,
    const float* w1, const float* b1, const float* nw, const float* nb,
    float* rn, float* sn){
  int blk = blockIdx.x;            // b*L+p
  int b = blk >> 12, p = blk & 4095;
  int y = p >> 6, x = p & 63;
  int c = threadIdx.x;
  const float* Sp = S + (size_t)b*32*1024 + (size_t)(y>>1)*32 + (x>>1);
  const float* wr = w1 + c*32;
  float sv = b1[c];
  #pragma unroll
  for(int ci=0; ci<32; ci++) sv += Sp[(size_t)ci*1024] * wr[ci];
  float rv = R[((size_t)b*C64 + c)*L + p];
  float mr = wred_sum(rv) * (1.f/64.f);
  float ms = wred_sum(sv) * (1.f/64.f);
  float dr = rv - mr, dsv = sv - ms;
  float vr = wred_sum(dr*dr) * (1.f/64.f);
  float vs = wred_sum(dsv*dsv) * (1.f/64.f);
  float g = nw[c], be = nb[c];
  rn[(size_t)blk*C64 + c] = dr  * rsqrtf(vr + 1e-6f) * g + be;
  sn[(size_t)blk*C64 + c] = dsv * rsqrtf(vs + 1e-6f) * g + be;
}

// 2) pre[0:64]=q_w@rn ; pre[64:192]=kv_w@sn     [192 thr per pixel]
__global__ __launch_bounds__(192) void k_qkvproj(const float* rn, const float* sn,
    const float* qw, const float* kvw, float* pre){
  __shared__ float sr[64], ss[64];
  int blk = blockIdx.x; int tid = threadIdx.x;
  if(tid < 64) sr[tid] = rn[(size_t)blk*64 + tid];
  else if(tid < 128) ss[tid-64] = sn[(size_t)blk*64 + (tid-64)];
  __syncthreads();
  float acc = 0.f;
  if(tid < 64){
    const float* w = qw + tid*64;
    #pragma unroll 8
    for(int i=0;i<64;i++) acc += w[i]*sr[i];
  } else {
    const float* w = kvw + (size_t)(tid-64)*64;
    #pragma unroll 8
    for(int i=0;i<64;i++) acc += w[i]*ss[i];
  }
  pre[(size_t)blk*192 + tid] = acc;
}

// 3) depthwise 3x3 on pre -> qkv (channel-major)
__global__ __launch_bounds__(192) void k_dwqkv(const float* pre, const float* qdw,
    const float* kvdw, float* qkv){
  int blk = blockIdx.x; int b = blk>>12, p = blk&4095;
  int y = p>>6, x = p&63;
  int cc = threadIdx.x;
  const float* w = (cc<64) ? (qdw + cc*9) : (kvdw + (size_t)(cc-64)*9);
  float acc = 0.f;
  #pragma unroll
  for(int ky=0;ky<3;ky++){ int yy=y+ky-1; if((unsigned)yy>=64u) continue;
    #pragma unroll
    for(int kx=0;kx<3;kx++){ int xx=x+kx-1; if((unsigned)xx>=64u) continue;
      acc += pre[((size_t)(b<<12) + (yy<<6)+xx)*192 + cc] * w[ky*3+kx]; } }
  qkv[((size_t)b*192+cc)*L + p] = acc;
}

// 4) inverse L2 norms of q,k rows
__global__ __launch_bounds__(256) void k_rownorm(const float* qkv, float* inv){
  int row = blockIdx.x; int b = row>>7, cc = row&127;
  const float* src = qkv + ((size_t)b*192 + cc)*L;
  float s = 0.f;
  for(int i=threadIdx.x; i<L; i+=256){ float v = src[i]; s += v*v; }
  __shared__ float red[256];
  red[threadIdx.x] = s; __syncthreads();
  for(int st=128; st>0; st>>=1){ if(threadIdx.x<st) red[threadIdx.x]+=red[threadIdx.x+st]; __syncthreads(); }
  if(threadIdx.x==0) inv[row] = 1.f / fmaxf(sqrtf(red[0]), 1e-12f);
}

// 5) Gram G[c,d] = sum_l q[c,l] k[d,l]   (one block per (b,h))
__global__ __launch_bounds__(1024) void k_gram(const float* qkv, float* G){
  int bh = blockIdx.x; int b = bh>>1, h = bh&1;
  __shared__ float qt[32][129], kt[32][129];
  int tid = threadIdx.x;
  int c = tid>>5, d = tid&31;
  const float* qbase = qkv + ((size_t)b*192 + h*32)*L;
  const float* kbase = qkv + ((size_t)b*192 + 64 + h*32)*L;
  float acc = 0.f;
  for(int t0=0;t0<L;t0+=128){
    __syncthreads();
    for(int e=tid; e<4096; e+=1024){ int cr=e>>7, li=e&127;
      qt[cr][li] = qbase[(size_t)cr*L + t0 + li];
      kt[cr][li] = kbase[(size_t)cr*L + t0 + li]; }
    __syncthreads();
    #pragma unroll 8
    for(int li=0; li<128; li++) acc += qt[c][li]*kt[d][li];
  }
  G[((size_t)bh*32 + c)*32 + d] = acc;
}

// 6) softmax rows (normalize by L2 norms, scale by temperature)  [1 block]
__global__ __launch_bounds__(256) void k_softmax(float* G, const float* inv, const float* temp){
  int row = threadIdx.x;            // (b*2+h)*32+c
  int b = row>>6, h = (row>>5)&1, c = row&31;
  float* g = G + (size_t)row*32;
  float iq = inv[b*128 + h*32 + c];
  float tp = temp[h];
  float vals[32]; float m = -1e30f;
  #pragma unroll
  for(int d=0; d<32; d++){ float v = g[d]*iq*inv[b*128+64+h*32+d]*tp; vals[d]=v; m = fmaxf(m,v); }
  float s = 0.f;
  #pragma unroll
  for(int d=0; d<32; d++){ vals[d] = __expf(vals[d]-m); s += vals[d]; }
  float r = 1.f/s;
  #pragma unroll
  for(int d=0; d<32; d++) g[d] = vals[d]*r;
}

// 7) out[c,l] = sum_d attn[c,d] v[d,l]  -> aout pixel-major
__global__ __launch_bounds__(256) void k_attnout(const float* G, const float* qkv, float* aout){
  int blk = blockIdx.x;            // (b*2+h)*64 + lt
  int lt = blk & 63; int bh = blk >> 6; int b = bh>>1, h = bh&1;
  __shared__ float at[32][32];
  __shared__ float vt[32][65];
  int tid = threadIdx.x;
  for(int e=tid; e<1024; e+=256) ((float*)at)[e] = G[(size_t)bh*1024 + e];
  const float* vbase = qkv + ((size_t)b*192 + 128 + h*32)*L + lt*64;
  for(int e=tid; e<2048; e+=256){ int d=e>>6, li=e&63; vt[d][li] = vbase[(size_t)d*L + li]; }
  __syncthreads();
  int li = tid & 63; int c0 = tid >> 6;
  int p = lt*64 + li;
  for(int cc=c0; cc<32; cc+=4){
    float acc = 0.f;
    #pragma unroll
    for(int d=0; d<32; d++) acc += at[cc][d]*vt[d][li];
    aout[((size_t)(b<<12) + p)*64 + h*32 + cc] = acc;
  }
}

// 8) r = R + proj @ aout     (channel-major out)
__global__ __launch_bounds__(64) void k_projadd(const float* aout, const float* pw,
    const float* R, float* r){
  int blk = blockIdx.x; int b = blk>>12, p = blk&4095;
  int oc = threadIdx.x;
  __shared__ float s[64];
  s[oc] = aout[(size_t)blk*64 + oc];
  __syncthreads();
  float acc = R[((size_t)b*64+oc)*L + p];
  const float* w = pw + oc*64;
  #pragma unroll 8
  for(int i=0;i<64;i++) acc += w[i]*s[i];
  r[((size_t)b*64+oc)*L + p] = acc;
}

// 9) ln2 = LN_cf(r)  (pixel-major out)
__global__ __launch_bounds__(64) void k_ln2(const float* r, const float* nw, const float* nb, float* ln2){
  int blk = blockIdx.x; int b = blk>>12, p = blk&4095;
  int c = threadIdx.x;
  float v = r[((size_t)b*64+c)*L + p];
  float m = wred_sum(v)*(1.f/64.f);
  float d = v - m;
  float var = wred_sum(d*d)*(1.f/64.f);
  ln2[(size_t)blk*64 + c] = d*rsqrtf(var+1e-6f)*nw[c] + nb[c];
}

// 10) xpre = pin_w @ ln2  (64->340), 4-pixel tile, channel-major out
__global__ __launch_bounds__(384) void k_pin(const float* ln2, const float* pw, float* xpre){
  int blk = blockIdx.x;                 // Bn*1024
  int b = blk >> 10; int p0 = (blk & 1023)*4;
  __shared__ float s[4][64];
  int tid = threadIdx.x;
  if(tid < 256) s[tid>>6][tid&63] = ln2[((size_t)(b<<12)+p0+(tid>>6))*64 + (tid&63)];
  __syncthreads();
  if(tid < DIN){
    const float* w = pw + (size_t)tid*64;
    float a0=0,a1=0,a2=0,a3=0;
    #pragma unroll 8
    for(int i=0;i<64;i++){ float wv=w[i]; a0+=wv*s[0][i]; a1+=wv*s[1][i]; a2+=wv*s[2][i]; a3+=wv*s[3][i]; }
    size_t base = ((size_t)b*DIN + tid)*L + p0;
    xpre[base]=a0; xpre[base+1]=a1; xpre[base+2]=a2; xpre[base+3]=a3;
  }
}

// 11) generic depthwise 3x3, channel-major -> channel-major
__global__ __launch_bounds__(256) void k_dw_cm(const float* in, const float* w9, float* out, int nch){
  int blk = blockIdx.x;
  int pt = blk & 15; int row = blk >> 4;     // row = b*nch + c
  int c = row % nch;
  const float* w = w9 + (size_t)c*9;
  int p = pt*256 + threadIdx.x;
  int y = p>>6, x = p&63;
  const float* base = in + (size_t)row*L;
  float acc = 0.f;
  #pragma unroll
  for(int ky=0;ky<3;ky++){ int yy=y+ky-1; if((unsigned)yy>=64u) continue;
    #pragma unroll
    for(int kx=0;kx<3;kx++){ int xx=x+kx-1; if((unsigned)xx>=64u) continue;
      acc += base[(yy<<6)+xx]*w[ky*3+kx]; } }
  out[(size_t)row*L + p] = acc;
}

// 12) r2 = LN_last(x1) over 170 ch (ln1, eps 1e-6), pixel-major out
__global__ __launch_bounds__(256) void k_ln1(const float* xd, const float* w, const float* bb, float* r2){
  int blk = blockIdx.x; int b = blk>>12, p = blk&4095;
  int tid = threadIdx.x;
  __shared__ float red[256]; __shared__ float smu, siv;
  float v = (tid<HID) ? xd[((size_t)b*DIN + tid)*L + p] : 0.f;
  red[tid] = v; __syncthreads();
  for(int st=128;st>0;st>>=1){ if(tid<st) red[tid]+=red[tid+st]; __syncthreads(); }
  if(tid==0) smu = red[0]*(1.f/HID);
  __syncthreads();
  float d = (tid<HID) ? v - smu : 0.f;
  red[tid] = d*d; __syncthreads();
  for(int st=128;st>0;st>>=1){ if(tid<st) red[tid]+=red[tid+st]; __syncthreads(); }
  if(tid==0) siv = rsqrtf(red[0]*(1.f/HID) + 1e-6f);
  __syncthreads();
  if(tid<HID) r2[(size_t)blk*HID + tid] = d*siv*w[tid] + bb[tid];
}

// 13) xxz = r2 @ in_w.T (170->680), 8-pixel tile, pixel-major out
__global__ __launch_bounds__(704) void k_inproj(const float* r2, const float* inw, float* xxz){
  int blk = blockIdx.x;                 // Bn*512
  int b = blk >> 9; int p0 = (blk & 511)*8;
  __shared__ float s[8][HID];
  int tid = threadIdx.x;
  for(int e=tid; e<8*HID; e+=704){ int px=e/HID, i=e-px*HID;
    s[px][i] = r2[((size_t)(b<<12)+p0+px)*HID + i]; }
  __syncthreads();
  if(tid < 680){
    const float* w = inw + (size_t)tid*HID;
    float acc[8] = {0,0,0,0,0,0,0,0};
    for(int i=0;i<HID;i++){ float wv = w[i];
      #pragma unroll
      for(int j=0;j<8;j++) acc[j] += wv*s[j][i]; }
    #pragma unroll
    for(int j=0;j<8;j++) xxz[((size_t)(b<<12)+p0+j)*680 + tid] = acc[j];
  }
}

// 14) xconvT = silu(dw3x3(xx)+bias), pixel-major out
__global__ __launch_bounds__(384) void k_dwss(const float* xxz, const float* w9,
    const float* bias, float* xcv){
  int blk = blockIdx.x; int b = blk>>12, p = blk&4095;
  int y = p>>6, x = p&63;
  int c = threadIdx.x;
  if(c < DIN){
    const float* w = w9 + (size_t)c*9;
    float acc = bias[c];
    #pragma unroll
    for(int ky=0;ky<3;ky++){ int yy=y+ky-1; if((unsigned)yy>=64u) continue;
      #pragma unroll
      for(int kx=0;kx<3;kx++){ int xx=x+kx-1; if((unsigned)xx>=64u) continue;
        acc += xxz[((size_t)(b<<12)+(yy<<6)+xx)*680 + c]*w[ky*3+kx]; } }
    xcv[(size_t)blk*DIN + c] = acc/(1.f+__expf(-acc));
  }
}

// 15) xdbl[b,k,l,0:43] = xpw[k] @ xs[b,k,:,l]   (8 l's per block)
__global__ __launch_bounds__(384) void k_xdbl(const float* xcv, const float* xpw, float* xdbl){
  int blk = blockIdx.x;                 // Bn*KD*512
  int lt = blk & 511; int bk = blk >> 9; int b = bk >> 2, k = bk & 3;
  __shared__ float s[8][DIN];
  int tid = threadIdx.x;
  int l0 = lt*8;
  for(int e=tid; e<8*DIN; e+=384){ int ls=e/DIN, d=e-ls*DIN;
    s[ls][d] = xcv[((size_t)(b<<12) + pmap(k, l0+ls))*DIN + d]; }
  __syncthreads();
  if(tid < 8*XD){ int ls = tid/XD, cc = tid - ls*XD;
    const float* w = xpw + ((size_t)k*XD + cc)*DIN;
    float acc = 0.f;
    for(int d=0; d<DIN; d++) acc += w[d]*s[ls][d];
    xdbl[((size_t)bk*L + l0+ls)*XDP + cc] = acc; }
}

// 16a) scan pass 1: per-chunk local scan (h0=0), local y via atomicAdd,
//      emit per-chunk h_end (16) and sum-of-dt
__global__ __launch_bounds__(64) void k_scan1(const float* xcv, const float* xdbl,
    const float* dtw, const float* dtb, const float* Alog, const float* Dss,
    float* yc, float* hend, float* sdt){
  int blk = blockIdx.x;                 // ((bk*6 + dchunk)*NCH + c)
  int c = blk % NCH; int t = blk / NCH;
  int dchunk = t % 6; int bk = t / 6; int b = bk>>2, k = bk&3;
  int d = dchunk*64 + threadIdx.x;
  bool act = d < DIN;
  int kd = k*DIN + (act ? d : 0);
  float A[NST], h[NST], wdt[DTR];
  float dtbv = 0.f, Dv = 0.f;
  #pragma unroll
  for(int n=0;n<NST;n++){ h[n] = 0.f; A[n] = 0.f; }
  #pragma unroll
  for(int r=0;r<DTR;r++) wdt[r] = 0.f;
  if(act){
    #pragma unroll
    for(int n=0;n<NST;n++) A[n] = -__expf(Alog[(size_t)kd*NST + n]);
    #pragma unroll
    for(int r=0;r<DTR;r++) wdt[r] = dtw[(size_t)kd*DTR + r];
    dtbv = dtb[kd]; Dv = Dss[kd];
  }
  __shared__ float row[8*XDP];
  const float* xrow = xdbl + (size_t)bk*L*XDP;
  const float* xc   = xcv + (size_t)(b<<12)*DIN;
  float* ycb = yc + (size_t)(b<<12)*DIN;
  float sdtacc = 0.f;
  int lbase = c*CLEN;
  for(int l0=lbase; l0<lbase+CLEN; l0+=8){
    __syncthreads();
    for(int e=threadIdx.x; e<8*XDP; e+=64) row[e] = xrow[(size_t)l0*XDP + e];
    __syncthreads();
    for(int ls=0; ls<8; ls++){
      int l = l0 + ls;
      const float* rw = &row[ls*XDP];
      float dt = dtbv;
      #pragma unroll
      for(int rr=0;rr<DTR;rr++) dt += wdt[rr]*rw[rr];
      dt = softplus_f(dt);
      sdtacc += dt;
      int p = pmap(k, l);
      float u = act ? xc[(size_t)p*DIN + d] : 0.f;
      float du = dt*u;
      float yv = Dv*u;
      #pragma unroll
      for(int n=0;n<NST;n++){
        float e_ = __expf(A[n]*dt);
        h[n] = e_*h[n] + du*rw[DTR+n];
        yv += h[n]*rw[DTR+NST+n];
      }
      if(act) atomicAdd(&ycb[(size_t)p*DIN + d], yv);
    }
  }
  if(act){
    size_t base = ((size_t)(bk*NCH + c)*NST)*DIN + d;
    #pragma unroll
    for(int n=0;n<NST;n++) hend[base + (size_t)n*DIN] = h[n];
    sdt[(size_t)(bk*NCH + c)*DIN + d] = sdtacc;
  }
}

// 16b) combine: sequential over chunks; hend -> hin in place
__global__ __launch_bounds__(64) void k_scomb(const float* Alog, float* hend, const float* sdt){
  int blk = blockIdx.x;                 // bk*6 + dchunk
  int dchunk = blk % 6; int bk = blk / 6; int k = bk & 3;
  int d = dchunk*64 + threadIdx.x;
  if(d >= DIN) return;
  int kd = k*DIN + d;
  float A[NST], run[NST];
  #pragma unroll
  for(int n=0;n<NST;n++){ A[n] = -__expf(Alog[(size_t)kd*NST + n]); run[n] = 0.f; }
  for(int c=0;c<NCH;c++){
    size_t base = ((size_t)(bk*NCH + c)*NST)*DIN + d;
    float s = sdt[(size_t)(bk*NCH + c)*DIN + d];
    #pragma unroll
    for(int n=0;n<NST;n++){
      float tmp = hend[base + (size_t)n*DIN];
      hend[base + (size_t)n*DIN] = run[n];
      run[n] = __expf(A[n]*s)*run[n] + tmp;
    }
  }
}

// 16c) scan pass 2: add initial-state correction  y_l += sum_n C_l[n]*hin[n]*exp(A[n]*cumdt_l)
__global__ __launch_bounds__(64) void k_scan2(const float* xdbl,
    const float* dtw, const float* dtb, const float* Alog,
    const float* hin, float* yc){
  int blk = blockIdx.x;                 // ((bk*6 + dchunk)*(NCH-1) + (c-1))
  int c = 1 + blk % (NCH-1); int t = blk / (NCH-1);
  int dchunk = t % 6; int bk = t / 6; int b = bk>>2, k = bk&3;
  int d = dchunk*64 + threadIdx.x;
  bool act = d < DIN;
  int kd = k*DIN + (act ? d : 0);
  float A[NST], hv[NST], wdt[DTR];
  float dtbv = 0.f;
  #pragma unroll
  for(int n=0;n<NST;n++){ A[n] = 0.f; hv[n] = 0.f; }
  #pragma unroll
  for(int r=0;r<DTR;r++) wdt[r] = 0.f;
  if(act){
    #pragma unroll
    for(int n=0;n<NST;n++) A[n] = -__expf(Alog[(size_t)kd*NST + n]);
    #pragma unroll
    for(int r=0;r<DTR;r++) wdt[r] = dtw[(size_t)kd*DTR + r];
    dtbv = dtb[kd];
    size_t base = ((size_t)(bk*NCH + c)*NST)*DIN + d;
    #pragma unroll
    for(int n=0;n<NST;n++) hv[n] = hin[base + (size_t)n*DIN];
  }
  __shared__ float row[8*XDP];
  const float* xrow = xdbl + (size_t)bk*L*XDP;
  float* ycb = yc + (size_t)(b<<12)*DIN;
  float cum = 0.f;
  int lbase = c*CLEN;
  for(int l0=lbase; l0<lbase+CLEN; l0+=8){
    __syncthreads();
    for(int e=threadIdx.x; e<8*XDP; e+=64) row[e] = xrow[(size_t)l0*XDP + e];
    __syncthreads();
    for(int ls=0; ls<8; ls++){
      int l = l0 + ls;
      const float* rw = &row[ls*XDP];
      float dt = dtbv;
      #pragma unroll
      for(int rr=0;rr<DTR;rr++) dt += wdt[rr]*rw[rr];
      dt = softplus_f(dt);
      cum += dt;
      float yv = 0.f;
      #pragma unroll
      for(int n=0;n<NST;n++) yv += hv[n]*__expf(A[n]*cum)*rw[DTR+NST+n];
      if(act){
        int p = pmap(k, l);
        atomicAdd(&ycb[(size_t)p*DIN + d], yv);
      }
    }
  }
}

// 17) x2t = tanh(dw3x3(x2)) + x2   (pixel-major out)
__global__ __launch_bounds__(256) void k_x2t(const float* xd, const float* w9, float* x2t){
  int blk = blockIdx.x;
  int pt = blk & 15; int g = blk >> 4;       // g = b*HID + c
  int b = g / HID, c = g - b*HID;
  int p = pt*256 + threadIdx.x;
  int y = p>>6, x = p&63;
  const float* base = xd + ((size_t)b*DIN + HID + c)*L;
  const float* w = w9 + (size_t)c*9;
  float acc = 0.f;
  #pragma unroll
  for(int ky=0;ky<3;ky++){ int yy=y+ky-1; if((unsigned)yy>=64u) continue;
    #pragma unroll
    for(int kx=0;kx<3;kx++){ int xx=x+kx-1; if((unsigned)xx>=64u) continue;
      acc += base[(yy<<6)+xx]*w[ky*3+kx]; } }
  x2t[((size_t)(b<<12)+p)*HID + c] = tanhf(acc) + base[p];
}

// 18) t = LN(y; onorm, eps 1e-5) * silu(z)   -- in place over ycomb
__global__ __launch_bounds__(256) void k_yln(float* yc, const float* xxz,
    const float* ow, const float* ob){
  int blk = blockIdx.x; int tid = threadIdx.x;
  __shared__ float yv[DIN]; __shared__ float red[256]; __shared__ float smu, siv;
  float* dst = yc + (size_t)blk*DIN;
  float s = 0.f;
  for(int i=tid;i<DIN;i+=256){ float v = dst[i]; yv[i] = v; s += v; }
  red[tid] = s; __syncthreads();
  for(int st=128;st>0;st>>=1){ if(tid<st) red[tid]+=red[tid+st]; __syncthreads(); }
  if(tid==0) smu = red[0]*(1.f/DIN);
  __syncthreads();
  s = 0.f;
  for(int i=tid;i<DIN;i+=256){ float d = yv[i]-smu; s += d*d; }
  red[tid] = s; __syncthreads();
  for(int st=128;st>0;st>>=1){ if(tid<st) red[tid]+=red[tid+st]; __syncthreads(); }
  if(tid==0) siv = rsqrtf(red[0]*(1.f/DIN) + 1e-5f);
  __syncthreads();
  const float* zp = xxz + (size_t)blk*680 + DIN;
  for(int i=tid;i<DIN;i+=256){
    float zz = zp[i];
    float lnv = (yv[i]-smu)*siv*ow[i] + ob[i];
    dst[i] = lnv * (zz/(1.f+__expf(-zz)));
  }
}

// 19) sso = t @ outw.T (340->170), 8-pixel tile, pixel-major out
__global__ __launch_bounds__(256) void k_outproj(const float* t, const float* ow, float* sso){
  int blk = blockIdx.x;                 // Bn*512
  int b = blk >> 9; int p0 = (blk & 511)*8;
  __shared__ float s[8][DIN];
  int tid = threadIdx.x;
  for(int e=tid; e<8*DIN; e+=256){ int px=e/DIN, i=e-px*DIN;
    s[px][i] = t[((size_t)(b<<12)+p0+px)*DIN + i]; }
  __syncthreads();
  if(tid < HID){
    const float* w = ow + (size_t)tid*DIN;
    float acc[8] = {0,0,0,0,0,0,0,0};
    for(int i=0;i<DIN;i++){ float wv = w[i];
      #pragma unroll
      for(int j=0;j<8;j++) acc[j] += wv*s[j][i]; }
    #pragma unroll
    for(int j=0;j<8;j++) sso[((size_t)(b<<12)+p0+j)*HID + tid] = acc[j];
  }
}

// 20) out = r + pout_w @ ((tanh(sso)+x1) * x2t)    (4-pixel tile)
__global__ __launch_bounds__(256) void k_final(const float* sso, const float* xd,
    const float* x2t, const float* pw, const float* r, float* out){
  int blk = blockIdx.x;                 // Bn*1024
  int b = blk >> 10; int p0 = (blk & 1023)*4;
  __shared__ float m[4][HID];
  int tid = threadIdx.x;
  for(int e=tid; e<4*HID; e+=256){ int px=e/HID, cc=e-px*HID;
    int p = p0 + px;
    float x1 = xd[((size_t)b*DIN + cc)*L + p];
    float s1 = tanhf(sso[((size_t)(b<<12)+p)*HID + cc]) + x1;
    m[px][cc] = s1 * x2t[((size_t)(b<<12)+p)*HID + cc];
  }
  __syncthreads();
  int oc = tid & 63, px = tid >> 6;
  const float* w = pw + (size_t)oc*HID;
  float acc = r[((size_t)b*64+oc)*L + p0+px];
  for(int i=0;i<HID;i++) acc += w[i]*m[px][i];
  out[((size_t)b*64+oc)*L + p0+px] = acc;
}

extern "C" void kernel_launch(void* const* d_in, const int* in_sizes, int n_in,
                              void* d_out, int out_size, void* d_ws, size_t ws_size,
                              hipStream_t stream) {
  const float* R     = (const float*)d_in[0];
  const float* S     = (const float*)d_in[1];
  const float* c1w   = (const float*)d_in[2];
  const float* c1b   = (const float*)d_in[3];
  const float* n1w   = (const float*)d_in[4];
  const float* n1b   = (const float*)d_in[5];
  const float* n2w   = (const float*)d_in[6];
  const float* n2b   = (const float*)d_in[7];
  const float* temp  = (const float*)d_in[8];
  const float* qw    = (const float*)d_in[9];
  const float* qdw   = (const float*)d_in[10];
  const float* kvw   = (const float*)d_in[11];
  const float* kvdw  = (const float*)d_in[12];
  const float* pjw   = (const float*)d_in[13];
  const float* pinw  = (const float*)d_in[14];
  const float* dww   = (const float*)d_in[15];
  const float* dw2w  = (const float*)d_in[16];
  const float* poutw = (const float*)d_in[17];
  const float* ln1w  = (const float*)d_in[18];
  const float* ln1b  = (const float*)d_in[19];
  const float* inw   = (const float*)d_in[20];
  const float* scw   = (const float*)d_in[21];
  const float* scb   = (const float*)d_in[22];
  const float* xpw   = (const float*)d_in[23];
  const float* dtw   = (const float*)d_in[24];
  const float* dtb   = (const float*)d_in[25];
  const float* Alog  = (const float*)d_in[26];
  const float* Dss   = (const float*)d_in[27];
  const float* onw   = (const float*)d_in[28];
  const float* onb   = (const float*)d_in[29];
  const float* outw  = (const float*)d_in[30];
  float* ws  = (float*)d_ws;
  float* out = (float*)d_out;

  float* rn   = ws + o_rn;
  float* sn   = ws + o_sn;
  float* pre  = ws + o_pre;
  float* qkv  = ws + o_qkv;
  float* inv  = ws + o_inv;
  float* attn = ws + o_attn;
  float* aout = ws + o_aout;
  float* r    = ws + o_r;
  float* ln2  = ws + o_ln2;
  float* xpre = ws + o_xpre;
  float* xd   = ws + o_xd;
  float* r2   = ws + o_r2;
  float* xxz  = ws + o_xxz;
  float* xcv  = ws + o_xcv;
  float* xdbl = ws + o_xdbl;
  float* yc   = ws + o_yc;
  float* sso  = ws + o_sso;
  float* x2t  = ws + o_x2t;
  float* hend = ws + o_r2;     // scan temp: aliases dead r2
  float* sdt  = ws + o_ln2;    // scan temp: aliases dead ln2

  // attention branch
  k_upln   <<<Bn*L, 64, 0, stream>>>(R, S, c1w, c1b, n1w, n1b, rn, sn);
  k_qkvproj<<<Bn*L, 192, 0, stream>>>(rn, sn, qw, kvw, pre);
  k_dwqkv  <<<Bn*L, 192, 0, stream>>>(pre, qdw, kvdw, qkv);
  k_rownorm<<<Bn*128, 256, 0, stream>>>(qkv, inv);
  k_gram   <<<Bn*2, 1024, 0, stream>>>(qkv, attn);
  k_softmax<<<1, 256, 0, stream>>>(attn, inv, temp);
  k_attnout<<<Bn*2*64, 256, 0, stream>>>(attn, qkv, aout);
  k_projadd<<<Bn*L, 64, 0, stream>>>(aout, pjw, R, r);
  // IEL branch
  k_ln2    <<<Bn*L, 64, 0, stream>>>(r, n2w, n2b, ln2);
  k_pin    <<<Bn*(L/4), 384, 0, stream>>>(ln2, pinw, xpre);
  k_dw_cm  <<<Bn*DIN*16, 256, 0, stream>>>(xpre, dww, xd, DIN);
  k_ln1    <<<Bn*L, 256, 0, stream>>>(xd, ln1w, ln1b, r2);
  // SS2D
  k_inproj <<<Bn*(L/8), 704, 0, stream>>>(r2, inw, xxz);
  k_dwss   <<<Bn*L, 384, 0, stream>>>(xxz, scw, scb, xcv);
  k_xdbl   <<<Bn*KD*(L/8), 384, 0, stream>>>(xcv, xpw, xdbl);
  hipMemsetAsync(yc, 0, (size_t)Bn*L*DIN*sizeof(float), stream);
  k_scan1  <<<16*6*NCH, 64, 0, stream>>>(xcv, xdbl, dtw, dtb, Alog, Dss, yc, hend, sdt);
  k_scomb  <<<16*6, 64, 0, stream>>>(Alog, hend, sdt);
  k_scan2  <<<16*6*(NCH-1), 64, 0, stream>>>(xdbl, dtw, dtb, Alog, hend, yc);
  k_x2t    <<<Bn*HID*16, 256, 0, stream>>>(xd, dw2w, x2t);
  k_yln    <<<Bn*L, 256, 0, stream>>>(yc, xxz, onw, onb);
  k_outproj<<<Bn*(L/8), 256, 0, stream>>>(yc, outw, sso);
  k_final  <<<Bn*(L/4), 256, 0, stream>>>(sso, xd, x2t, poutw, r, out);
}

// Round 3
// 1285.527 us; speedup vs baseline: 4.4807x; 1.1725x over previous
//
#include <hip/hip_runtime.h>
#include <math.h>

#define DEV __device__ __forceinline__

constexpr int Bn  = 4;
constexpr int C64 = 64;
constexpr int L   = 4096;     // 64*64
constexpr int HID = 170;
constexpr int DIN = 340;
constexpr int NST = 16;
constexpr int DTR = 11;
constexpr int KD  = 4;
constexpr int XD  = 43;       // DTR + 2*NST
constexpr int XDP = 44;       // padded stride
constexpr int NCH = 32;       // scan chunks
constexpr int CLEN = L / NCH; // 128 steps per chunk

// ---- workspace layout (floats) ----
constexpr size_t o_rn   = 0;                       // B*L*64   (pixel-major)
constexpr size_t o_sn   = o_rn  + (size_t)Bn*L*C64;
constexpr size_t o_pre  = o_sn  + (size_t)Bn*L*C64;        // B*L*192 pixel-major
constexpr size_t o_xcv  = 0;                       // phase2: xconvT B*L*340 pixel-major (reuses rn/sn/pre)
constexpr size_t regA_end = (size_t)Bn*L*DIN;              // 5,570,560
constexpr size_t o_qkv  = regA_end;                        // B*192*L channel-major
constexpr size_t o_xdbl = regA_end;                        // phase2: B*K*L*44
constexpr size_t regB_end = o_qkv + (size_t)Bn*192*L;      // 8,716,288
constexpr size_t o_inv  = regB_end;                        // 512
constexpr size_t o_attn = o_inv + 512;                     // 8192
constexpr size_t o_aout = o_attn + 8192;                   // B*L*64 pixel-major
constexpr size_t o_r    = o_aout + (size_t)Bn*L*C64;       // channel-major
constexpr size_t o_ln2  = o_r    + (size_t)Bn*L*C64;       // pixel-major; phase2: sdt
constexpr size_t o_xpre = o_ln2  + (size_t)Bn*L*C64;       // B*L*340 pixel-major
constexpr size_t o_yc   = o_xpre;                          // phase2: ycomb B*L*340 pixel-major (then t in-place)
constexpr size_t o_xd   = o_xpre + (size_t)Bn*DIN*L;       // B*L*340 pixel-major
constexpr size_t o_r2   = o_xd   + (size_t)Bn*DIN*L;       // B*L*170 pixel-major; phase2: hend/hin
constexpr size_t o_sso  = o_r2;                            // phase3: B*L*170 pixel-major
constexpr size_t o_xxz  = o_r2   + (size_t)Bn*L*HID;       // B*L*680 pixel-major
constexpr size_t o_x2t  = o_xxz  + (size_t)Bn*L*680;       // B*L*170 pixel-major
constexpr size_t WS_FLOATS = o_x2t + (size_t)Bn*L*HID;     // ~158.9 MB

DEV float wred_sum(float v){
  #pragma unroll
  for(int s=32;s>0;s>>=1) v += __shfl_xor(v, s, 64);
  return v;
}

DEV int pmap(int k, int l){
  switch(k){
    case 0:  return l;
    case 1:  return ((l&63)<<6) | (l>>6);
    case 2:  return 4095 - l;
    default: { int t = 4095 - l; return ((t&63)<<6) | (t>>6); }
  }
}

DEV float softplus_f(float x){
  return (x > 20.f) ? x : __logf(1.f + __expf(x));
}

// ======================= tiled fp32 GEMM =======================
// C[M][N] = X[M][K] * W[N][K]^T, pixel-major in/out.
// 256 threads, BM=128, BN=128 (TN=8) or 64 (TN=4), TM=8, KC=32.
// MODE 0: plain. MODE 1: xdbl (pmap row gather, C stride 44).
// MODE 2: final (fused staging from sso/xd/x2t, epilogue transpose + r add -> out).
template<int MODE, int BN>
__global__ __launch_bounds__(256) void k_gemm(
    const float* __restrict__ X, const float* __restrict__ W, float* __restrict__ C,
    const float* __restrict__ e1, const float* __restrict__ e2, const float* __restrict__ e3,
    int N, int K, int ldx, int ldc, int ntn){
  constexpr int KC = 32, BM = 128, BMP = 132, BNP = BN + 4;
  constexpr int TN = (BN == 128) ? 8 : 4;
  constexpr int SM_STAGE = KC*BMP + KC*BNP;
  constexpr int SM_TOT = (MODE==2) ? (SM_STAGE > 64*BMP ? SM_STAGE : 64*BMP) : SM_STAGE;
  __shared__ __align__(16) float sm[SM_TOT];
  float* Xs = sm;
  float* Ws = sm + KC*BMP;

  int blk = blockIdx.x;
  int tid = threadIdx.x;
  int tx = tid & 15, ty = tid >> 4;

  int Mbase = 0, Nbase = 0, Lbase = 0, bq = 0, kdir = 0;
  const float* Wp = W;
  float* Cp = C;
  if(MODE == 1){
    int bk = blk >> 5; int mt = blk & 31;
    Lbase = mt * BM; bq = bk >> 2; kdir = bk & 3;
    Wp = W + (size_t)kdir * XD * DIN;
    Cp = C + (size_t)bk * L * XDP;
  } else {
    int mt = blk / ntn; int nt = blk % ntn;
    Mbase = mt * BM; Nbase = nt * BN;
  }

  float acc[8][TN];
  #pragma unroll
  for(int i=0;i<8;i++)
    #pragma unroll
    for(int j=0;j<TN;j++) acc[i][j] = 0.f;

  for(int kc0 = 0; kc0 < K; kc0 += KC){
    __syncthreads();
    // stage X tile (k-major in LDS)
    #pragma unroll
    for(int e = tid; e < BM*KC; e += 256){
      int p = e >> 5, k = e & 31, gk = kc0 + k;
      float v = 0.f;
      if(gk < K){
        if(MODE == 0){
          v = X[(size_t)(Mbase + p)*ldx + gk];
        } else if(MODE == 1){
          int pp = pmap(kdir, Lbase + p);
          v = X[((size_t)(bq<<12) + pp)*DIN + gk];
        } else {
          size_t rp = (size_t)(Mbase + p);
          v = (tanhf(X[rp*HID + gk]) + e1[rp*DIN + gk]) * e2[rp*HID + gk];
        }
      }
      Xs[k*BMP + p] = v;
    }
    // stage W tile
    #pragma unroll
    for(int e = tid; e < BN*KC; e += 256){
      int o = e >> 5, k = e & 31, gk = kc0 + k;
      int go = Nbase + o;
      float v = 0.f;
      if(gk < K && go < N) v = Wp[(size_t)go*K + gk];
      Ws[k*BNP + o] = v;
    }
    __syncthreads();
    #pragma unroll 4
    for(int k=0;k<KC;k++){
      const float4 a0 = *(const float4*)&Xs[k*BMP + ty*4];
      const float4 a1 = *(const float4*)&Xs[k*BMP + 64 + ty*4];
      const float4 b0 = *(const float4*)&Ws[k*BNP + tx*4];
      float4 b1;
      if(BN == 128) b1 = *(const float4*)&Ws[k*BNP + 64 + tx*4];
      #pragma unroll
      for(int i=0;i<4;i++){
        float av0 = ((const float*)&a0)[i];
        float av1 = ((const float*)&a1)[i];
        #pragma unroll
        for(int j=0;j<4;j++){
          float bv = ((const float*)&b0)[j];
          acc[i][j]   += av0*bv;
          acc[i+4][j] += av1*bv;
          if(BN == 128){
            float bv1 = ((const float*)&b1)[j];
            acc[i][j+4]   += av0*bv1;
            acc[i+4][j+4] += av1*bv1;
          }
        }
      }
    }
  }

  if(MODE == 2){
    // transpose via LDS, then coalesced channel-major store with r add
    __syncthreads();
    float* Cs = sm;
    #pragma unroll
    for(int i=0;i<8;i++){
      int p = (i<4) ? (ty*4 + i) : (60 + ty*4 + i);
      #pragma unroll
      for(int j=0;j<TN;j++){
        int oc = tx*4 + j;
        Cs[oc*BMP + p] = acc[i][j];
      }
    }
    __syncthreads();
    int b = Mbase >> 12; int p0 = Mbase & 4095;
    for(int e = tid; e < 64*BM; e += 256){
      int p = e & 127; int oc = e >> 7;
      size_t gi = ((size_t)b*64 + oc)*L + p0 + p;
      C[gi] = e3[gi] + Cs[oc*BMP + p];
    }
  } else {
    #pragma unroll
    for(int i=0;i<8;i++){
      int pl = (i<4) ? (ty*4 + i) : (60 + ty*4 + i);
      size_t crow;
      if(MODE == 0) crow = (size_t)(Mbase + pl)*ldc;
      else          crow = (size_t)(Lbase + pl)*XDP;
      #pragma unroll
      for(int h=0; h<(BN==128?2:1); h++){
        int col = Nbase + h*64 + tx*4;
        float4 v;
        v.x = acc[i][h*4+0]; v.y = acc[i][h*4+1];
        v.z = acc[i][h*4+2]; v.w = acc[i][h*4+3];
        if(MODE == 1){
          if(col + 3 < XDP) *(float4*)&Cp[crow + col] = v;
        } else {
          if(((ldc & 3) == 0) && (col + 3 < N)){
            *(float4*)&Cp[crow + col] = v;
          } else {
            #pragma unroll
            for(int j=0;j<4;j++) if(col + j < N) Cp[crow + col + j] = acc[i][h*4+j];
          }
        }
      }
    }
  }
}

// 1) s = conv1(upsample(S)); r_n = LN_cf(R); s_n = LN_cf(s)   [64 thr = one pixel]
__global__ __launch_bounds__(64) void k_upln(const float* R, const float* S,
    const float* w1, const float* b1, const float* nw, const float* nb,
    float* rn, float* sn){
  int blk = blockIdx.x;            // b*L+p
  int b = blk >> 12, p = blk & 4095;
  int y = p >> 6, x = p & 63;
  int c = threadIdx.x;
  const float* Sp = S + (size_t)b*32*1024 + (size_t)(y>>1)*32 + (x>>1);
  const float* wr = w1 + c*32;
  float sv = b1[c];
  #pragma unroll
  for(int ci=0; ci<32; ci++) sv += Sp[(size_t)ci*1024] * wr[ci];
  float rv = R[((size_t)b*C64 + c)*L + p];
  float mr = wred_sum(rv) * (1.f/64.f);
  float ms = wred_sum(sv) * (1.f/64.f);
  float dr = rv - mr, dsv = sv - ms;
  float vr = wred_sum(dr*dr) * (1.f/64.f);
  float vs = wred_sum(dsv*dsv) * (1.f/64.f);
  float g = nw[c], be = nb[c];
  rn[(size_t)blk*C64 + c] = dr  * rsqrtf(vr + 1e-6f) * g + be;
  sn[(size_t)blk*C64 + c] = dsv * rsqrtf(vs + 1e-6f) * g + be;
}

// 2) pre[0:64]=q_w@rn ; pre[64:192]=kv_w@sn     [192 thr per pixel]
__global__ __launch_bounds__(192) void k_qkvproj(const float* rn, const float* sn,
    const float* qw, const float* kvw, float* pre){
  __shared__ float sr[64], ss[64];
  int blk = blockIdx.x; int tid = threadIdx.x;
  if(tid < 64) sr[tid] = rn[(size_t)blk*64 + tid];
  else if(tid < 128) ss[tid-64] = sn[(size_t)blk*64 + (tid-64)];
  __syncthreads();
  float acc = 0.f;
  if(tid < 64){
    const float* w = qw + tid*64;
    #pragma unroll 8
    for(int i=0;i<64;i++) acc += w[i]*sr[i];
  } else {
    const float* w = kvw + (size_t)(tid-64)*64;
    #pragma unroll 8
    for(int i=0;i<64;i++) acc += w[i]*ss[i];
  }
  pre[(size_t)blk*192 + tid] = acc;
}

// 3) depthwise 3x3 on pre -> qkv (channel-major)
__global__ __launch_bounds__(192) void k_dwqkv(const float* pre, const float* qdw,
    const float* kvdw, float* qkv){
  int blk = blockIdx.x; int b = blk>>12, p = blk&4095;
  int y = p>>6, x = p&63;
  int cc = threadIdx.x;
  const float* w = (cc<64) ? (qdw + cc*9) : (kvdw + (size_t)(cc-64)*9);
  float acc = 0.f;
  #pragma unroll
  for(int ky=0;ky<3;ky++){ int yy=y+ky-1; if((unsigned)yy>=64u) continue;
    #pragma unroll
    for(int kx=0;kx<3;kx++){ int xx=x+kx-1; if((unsigned)xx>=64u) continue;
      acc += pre[((size_t)(b<<12) + (yy<<6)+xx)*192 + cc] * w[ky*3+kx]; } }
  qkv[((size_t)b*192+cc)*L + p] = acc;
}

// 4) inverse L2 norms of q,k rows
__global__ __launch_bounds__(256) void k_rownorm(const float* qkv, float* inv){
  int row = blockIdx.x; int b = row>>7, cc = row&127;
  const float* src = qkv + ((size_t)b*192 + cc)*L;
  float s = 0.f;
  for(int i=threadIdx.x; i<L; i+=256){ float v = src[i]; s += v*v; }
  __shared__ float red[256];
  red[threadIdx.x] = s; __syncthreads();
  for(int st=128; st>0; st>>=1){ if(threadIdx.x<st) red[threadIdx.x]+=red[threadIdx.x+st]; __syncthreads(); }
  if(threadIdx.x==0) inv[row] = 1.f / fmaxf(sqrtf(red[0]), 1e-12f);
}

// 5) Gram G[c,d] = sum_l q[c,l] k[d,l]   (one block per (b,h))
__global__ __launch_bounds__(1024) void k_gram(const float* qkv, float* G){
  int bh = blockIdx.x; int b = bh>>1, h = bh&1;
  __shared__ float qt[32][129], kt[32][129];
  int tid = threadIdx.x;
  int c = tid>>5, d = tid&31;
  const float* qbase = qkv + ((size_t)b*192 + h*32)*L;
  const float* kbase = qkv + ((size_t)b*192 + 64 + h*32)*L;
  float acc = 0.f;
  for(int t0=0;t0<L;t0+=128){
    __syncthreads();
    for(int e=tid; e<4096; e+=1024){ int cr=e>>7, li=e&127;
      qt[cr][li] = qbase[(size_t)cr*L + t0 + li];
      kt[cr][li] = kbase[(size_t)cr*L + t0 + li]; }
    __syncthreads();
    #pragma unroll 8
    for(int li=0; li<128; li++) acc += qt[c][li]*kt[d][li];
  }
  G[((size_t)bh*32 + c)*32 + d] = acc;
}

// 6) softmax rows (normalize by L2 norms, scale by temperature)  [1 block]
__global__ __launch_bounds__(256) void k_softmax(float* G, const float* inv, const float* temp){
  int row = threadIdx.x;            // (b*2+h)*32+c
  int b = row>>6, h = (row>>5)&1, c = row&31;
  float* g = G + (size_t)row*32;
  float iq = inv[b*128 + h*32 + c];
  float tp = temp[h];
  float vals[32]; float m = -1e30f;
  #pragma unroll
  for(int d=0; d<32; d++){ float v = g[d]*iq*inv[b*128+64+h*32+d]*tp; vals[d]=v; m = fmaxf(m,v); }
  float s = 0.f;
  #pragma unroll
  for(int d=0; d<32; d++){ vals[d] = __expf(vals[d]-m); s += vals[d]; }
  float r = 1.f/s;
  #pragma unroll
  for(int d=0; d<32; d++) g[d] = vals[d]*r;
}

// 7) out[c,l] = sum_d attn[c,d] v[d,l]  -> aout pixel-major
__global__ __launch_bounds__(256) void k_attnout(const float* G, const float* qkv, float* aout){
  int blk = blockIdx.x;            // (b*2+h)*64 + lt
  int lt = blk & 63; int bh = blk >> 6; int b = bh>>1, h = bh&1;
  __shared__ float at[32][32];
  __shared__ float vt[32][65];
  int tid = threadIdx.x;
  for(int e=tid; e<1024; e+=256) ((float*)at)[e] = G[(size_t)bh*1024 + e];
  const float* vbase = qkv + ((size_t)b*192 + 128 + h*32)*L + lt*64;
  for(int e=tid; e<2048; e+=256){ int d=e>>6, li=e&63; vt[d][li] = vbase[(size_t)d*L + li]; }
  __syncthreads();
  int li = tid & 63; int c0 = tid >> 6;
  int p = lt*64 + li;
  for(int cc=c0; cc<32; cc+=4){
    float acc = 0.f;
    #pragma unroll
    for(int d=0; d<32; d++) acc += at[cc][d]*vt[d][li];
    aout[((size_t)(b<<12) + p)*64 + h*32 + cc] = acc;
  }
}

// 8) r = R + proj @ aout (channel-major out) fused with ln2 = LN_cf(r) (pixel-major out)
__global__ __launch_bounds__(64) void k_projln(const float* aout, const float* pw,
    const float* R, const float* nw, const float* nb, float* r, float* ln2){
  int blk = blockIdx.x; int b = blk>>12, p = blk&4095;
  int oc = threadIdx.x;
  __shared__ float s[64];
  s[oc] = aout[(size_t)blk*64 + oc];
  __syncthreads();
  float acc = R[((size_t)b*64+oc)*L + p];
  const float* w = pw + oc*64;
  #pragma unroll 8
  for(int i=0;i<64;i++) acc += w[i]*s[i];
  r[((size_t)b*64+oc)*L + p] = acc;
  float m = wred_sum(acc)*(1.f/64.f);
  float d = acc - m;
  float var = wred_sum(d*d)*(1.f/64.f);
  ln2[(size_t)blk*64 + oc] = d*rsqrtf(var+1e-6f)*nw[oc] + nb[oc];
}

// 11) dw3x3 on xpre (pixel-major) -> xd (pixel-major), fused LN over first 170 ch -> r2
__global__ __launch_bounds__(384) void k_dwx(const float* __restrict__ xpre, const float* __restrict__ w9,
    const float* __restrict__ lnw, const float* __restrict__ lnb,
    float* __restrict__ xd, float* __restrict__ r2){
  int blk = blockIdx.x; int b = blk>>12, p = blk&4095;
  int y = p>>6, x = p&63;
  int c = threadIdx.x;
  float acc = 0.f;
  if(c < DIN){
    const float* w = w9 + (size_t)c*9;
    #pragma unroll
    for(int ky=0;ky<3;ky++){ int yy=y+ky-1; if((unsigned)yy>=64u) continue;
      #pragma unroll
      for(int kx=0;kx<3;kx++){ int xx=x+kx-1; if((unsigned)xx>=64u) continue;
        acc += xpre[((size_t)(b<<12)+(yy<<6)+xx)*DIN + c]*w[ky*3+kx]; } }
    xd[((size_t)(b<<12)+p)*DIN + c] = acc;
  }
  __shared__ float red[384]; __shared__ float smu, siv;
  float v = (c < HID) ? acc : 0.f;
  red[c] = v; __syncthreads();
  if(c < 128) red[c] = red[c] + red[c+128] + red[c+256];
  __syncthreads();
  for(int st=64; st>0; st>>=1){ if(c<st) red[c]+=red[c+st]; __syncthreads(); }
  if(c==0) smu = red[0]*(1.f/HID);
  __syncthreads();
  float d = (c < HID) ? acc - smu : 0.f;
  red[c] = d*d; __syncthreads();
  if(c < 128) red[c] = red[c] + red[c+128] + red[c+256];
  __syncthreads();
  for(int st=64; st>0; st>>=1){ if(c<st) red[c]+=red[c+st]; __syncthreads(); }
  if(c==0) siv = rsqrtf(red[0]*(1.f/HID) + 1e-6f);
  __syncthreads();
  if(c < HID) r2[(size_t)blk*HID + c] = d*siv*lnw[c] + lnb[c];
}

// 14) xconvT = silu(dw3x3(xx)+bias), pixel-major out
__global__ __launch_bounds__(384) void k_dwss(const float* xxz, const float* w9,
    const float* bias, float* xcv){
  int blk = blockIdx.x; int b = blk>>12, p = blk&4095;
  int y = p>>6, x = p&63;
  int c = threadIdx.x;
  if(c < DIN){
    const float* w = w9 + (size_t)c*9;
    float acc = bias[c];
    #pragma unroll
    for(int ky=0;ky<3;ky++){ int yy=y+ky-1; if((unsigned)yy>=64u) continue;
      #pragma unroll
      for(int kx=0;kx<3;kx++){ int xx=x+kx-1; if((unsigned)xx>=64u) continue;
        acc += xxz[((size_t)(b<<12)+(yy<<6)+xx)*680 + c]*w[ky*3+kx]; } }
    xcv[(size_t)blk*DIN + c] = acc/(1.f+__expf(-acc));
  }
}

// 16a) scan pass 1: per-chunk local scan (h0=0), local y via atomicAdd,
//      emit per-chunk h_end (16) and sum-of-dt
__global__ __launch_bounds__(64) void k_scan1(const float* xcv, const float* xdbl,
    const float* dtw, const float* dtb, const float* Alog, const float* Dss,
    float* yc, float* hend, float* sdt){
  int blk = blockIdx.x;                 // ((bk*6 + dchunk)*NCH + c)
  int c = blk % NCH; int t = blk / NCH;
  int dchunk = t % 6; int bk = t / 6; int b = bk>>2, k = bk&3;
  int d = dchunk*64 + threadIdx.x;
  bool act = d < DIN;
  int kd = k*DIN + (act ? d : 0);
  float A[NST], h[NST], wdt[DTR];
  float dtbv = 0.f, Dv = 0.f;
  #pragma unroll
  for(int n=0;n<NST;n++){ h[n] = 0.f; A[n] = 0.f; }
  #pragma unroll
  for(int r=0;r<DTR;r++) wdt[r] = 0.f;
  if(act){
    #pragma unroll
    for(int n=0;n<NST;n++) A[n] = -__expf(Alog[(size_t)kd*NST + n]);
    #pragma unroll
    for(int r=0;r<DTR;r++) wdt[r] = dtw[(size_t)kd*DTR + r];
    dtbv = dtb[kd]; Dv = Dss[kd];
  }
  __shared__ float row[8*XDP];
  const float* xrow = xdbl + (size_t)bk*L*XDP;
  const float* xc   = xcv + (size_t)(b<<12)*DIN;
  float* ycb = yc + (size_t)(b<<12)*DIN;
  float sdtacc = 0.f;
  int lbase = c*CLEN;
  for(int l0=lbase; l0<lbase+CLEN; l0+=8){
    __syncthreads();
    for(int e=threadIdx.x; e<8*XDP; e+=64) row[e] = xrow[(size_t)l0*XDP + e];
    __syncthreads();
    for(int ls=0; ls<8; ls++){
      int l = l0 + ls;
      const float* rw = &row[ls*XDP];
      float dt = dtbv;
      #pragma unroll
      for(int rr=0;rr<DTR;rr++) dt += wdt[rr]*rw[rr];
      dt = softplus_f(dt);
      sdtacc += dt;
      int p = pmap(k, l);
      float u = act ? xc[(size_t)p*DIN + d] : 0.f;
      float du = dt*u;
      float yv = Dv*u;
      #pragma unroll
      for(int n=0;n<NST;n++){
        float e_ = __expf(A[n]*dt);
        h[n] = e_*h[n] + du*rw[DTR+n];
        yv += h[n]*rw[DTR+NST+n];
      }
      if(act) atomicAdd(&ycb[(size_t)p*DIN + d], yv);
    }
  }
  if(act){
    size_t base = ((size_t)(bk*NCH + c)*NST)*DIN + d;
    #pragma unroll
    for(int n=0;n<NST;n++) hend[base + (size_t)n*DIN] = h[n];
    sdt[(size_t)(bk*NCH + c)*DIN + d] = sdtacc;
  }
}

// 16b) combine: sequential over chunks; hend -> hin in place
__global__ __launch_bounds__(64) void k_scomb(const float* Alog, float* hend, const float* sdt){
  int blk = blockIdx.x;                 // bk*6 + dchunk
  int dchunk = blk % 6; int bk = blk / 6; int k = bk & 3;
  int d = dchunk*64 + threadIdx.x;
  if(d >= DIN) return;
  int kd = k*DIN + d;
  float A[NST], run[NST];
  #pragma unroll
  for(int n=0;n<NST;n++){ A[n] = -__expf(Alog[(size_t)kd*NST + n]); run[n] = 0.f; }
  for(int c=0;c<NCH;c++){
    size_t base = ((size_t)(bk*NCH + c)*NST)*DIN + d;
    float s = sdt[(size_t)(bk*NCH + c)*DIN + d];
    #pragma unroll
    for(int n=0;n<NST;n++){
      float tmp = hend[base + (size_t)n*DIN];
      hend[base + (size_t)n*DIN] = run[n];
      run[n] = __expf(A[n]*s)*run[n] + tmp;
    }
  }
}

// 16c) scan pass 2: add initial-state correction  y_l += sum_n C_l[n]*hin[n]*exp(A[n]*cumdt_l)
__global__ __launch_bounds__(64) void k_scan2(const float* xdbl,
    const float* dtw, const float* dtb, const float* Alog,
    const float* hin, float* yc){
  int blk = blockIdx.x;                 // ((bk*6 + dchunk)*(NCH-1) + (c-1))
  int c = 1 + blk % (NCH-1); int t = blk / (NCH-1);
  int dchunk = t % 6; int bk = t / 6; int b = bk>>2, k = bk&3;
  int d = dchunk*64 + threadIdx.x;
  bool act = d < DIN;
  int kd = k*DIN + (act ? d : 0);
  float A[NST], hv[NST], wdt[DTR];
  float dtbv = 0.f;
  #pragma unroll
  for(int n=0;n<NST;n++){ A[n] = 0.f; hv[n] = 0.f; }
  #pragma unroll
  for(int r=0;r<DTR;r++) wdt[r] = 0.f;
  if(act){
    #pragma unroll
    for(int n=0;n<NST;n++) A[n] = -__expf(Alog[(size_t)kd*NST + n]);
    #pragma unroll
    for(int r=0;r<DTR;r++) wdt[r] = dtw[(size_t)kd*DTR + r];
    dtbv = dtb[kd];
    size_t base = ((size_t)(bk*NCH + c)*NST)*DIN + d;
    #pragma unroll
    for(int n=0;n<NST;n++) hv[n] = hin[base + (size_t)n*DIN];
  }
  __shared__ float row[8*XDP];
  const float* xrow = xdbl + (size_t)bk*L*XDP;
  float* ycb = yc + (size_t)(b<<12)*DIN;
  float cum = 0.f;
  int lbase = c*CLEN;
  for(int l0=lbase; l0<lbase+CLEN; l0+=8){
    __syncthreads();
    for(int e=threadIdx.x; e<8*XDP; e+=64) row[e] = xrow[(size_t)l0*XDP + e];
    __syncthreads();
    for(int ls=0; ls<8; ls++){
      int l = l0 + ls;
      const float* rw = &row[ls*XDP];
      float dt = dtbv;
      #pragma unroll
      for(int rr=0;rr<DTR;rr++) dt += wdt[rr]*rw[rr];
      dt = softplus_f(dt);
      cum += dt;
      float yv = 0.f;
      #pragma unroll
      for(int n=0;n<NST;n++) yv += hv[n]*__expf(A[n]*cum)*rw[DTR+NST+n];
      if(act){
        int p = pmap(k, l);
        atomicAdd(&ycb[(size_t)p*DIN + d], yv);
      }
    }
  }
}

// 17) x2t = tanh(dw3x3(x2)) + x2   (pixel-major in/out)
__global__ __launch_bounds__(192) void k_x2t(const float* __restrict__ xd, const float* __restrict__ w9,
    float* __restrict__ x2t){
  int blk = blockIdx.x; int b = blk>>12, p = blk&4095;
  int y = p>>6, x = p&63;
  int c = threadIdx.x;
  if(c >= HID) return;
  const float* w = w9 + (size_t)c*9;
  float acc = 0.f;
  #pragma unroll
  for(int ky=0;ky<3;ky++){ int yy=y+ky-1; if((unsigned)yy>=64u) continue;
    #pragma unroll
    for(int kx=0;kx<3;kx++){ int xx=x+kx-1; if((unsigned)xx>=64u) continue;
      acc += xd[((size_t)(b<<12)+(yy<<6)+xx)*DIN + HID + c]*w[ky*3+kx]; } }
  size_t i = (size_t)(b<<12) + p;
  x2t[i*HID + c] = tanhf(acc) + xd[i*DIN + HID + c];
}

// 18) t = LN(y; onorm, eps 1e-5) * silu(z)   -- in place over ycomb
__global__ __launch_bounds__(256) void k_yln(float* yc, const float* xxz,
    const float* ow, const float* ob){
  int blk = blockIdx.x; int tid = threadIdx.x;
  __shared__ float yv[DIN]; __shared__ float red[256]; __shared__ float smu, siv;
  float* dst = yc + (size_t)blk*DIN;
  float s = 0.f;
  for(int i=tid;i<DIN;i+=256){ float v = dst[i]; yv[i] = v; s += v; }
  red[tid] = s; __syncthreads();
  for(int st=128;st>0;st>>=1){ if(tid<st) red[tid]+=red[tid+st]; __syncthreads(); }
  if(tid==0) smu = red[0]*(1.f/DIN);
  __syncthreads();
  s = 0.f;
  for(int i=tid;i<DIN;i+=256){ float d = yv[i]-smu; s += d*d; }
  red[tid] = s; __syncthreads();
  for(int st=128;st>0;st>>=1){ if(tid<st) red[tid]+=red[tid+st]; __syncthreads(); }
  if(tid==0) siv = rsqrtf(red[0]*(1.f/DIN) + 1e-5f);
  __syncthreads();
  const float* zp = xxz + (size_t)blk*680 + DIN;
  for(int i=tid;i<DIN;i+=256){
    float zz = zp[i];
    float lnv = (yv[i]-smu)*siv*ow[i] + ob[i];
    dst[i] = lnv * (zz/(1.f+__expf(-zz)));
  }
}

extern "C" void kernel_launch(void* const* d_in, const int* in_sizes, int n_in,
                              void* d_out, int out_size, void* d_ws, size_t ws_size,
                              hipStream_t stream) {
  const float* R     = (const float*)d_in[0];
  const float* S     = (const float*)d_in[1];
  const float* c1w   = (const float*)d_in[2];
  const float* c1b   = (const float*)d_in[3];
  const float* n1w   = (const float*)d_in[4];
  const float* n1b   = (const float*)d_in[5];
  const float* n2w   = (const float*)d_in[6];
  const float* n2b   = (const float*)d_in[7];
  const float* temp  = (const float*)d_in[8];
  const float* qw    = (const float*)d_in[9];
  const float* qdw   = (const float*)d_in[10];
  const float* kvw   = (const float*)d_in[11];
  const float* kvdw  = (const float*)d_in[12];
  const float* pjw   = (const float*)d_in[13];
  const float* pinw  = (const float*)d_in[14];
  const float* dww   = (const float*)d_in[15];
  const float* dw2w  = (const float*)d_in[16];
  const float* poutw = (const float*)d_in[17];
  const float* ln1w  = (const float*)d_in[18];
  const float* ln1b  = (const float*)d_in[19];
  const float* inw   = (const float*)d_in[20];
  const float* scw   = (const float*)d_in[21];
  const float* scb   = (const float*)d_in[22];
  const float* xpw   = (const float*)d_in[23];
  const float* dtw   = (const float*)d_in[24];
  const float* dtb   = (const float*)d_in[25];
  const float* Alog  = (const float*)d_in[26];
  const float* Dss   = (const float*)d_in[27];
  const float* onw   = (const float*)d_in[28];
  const float* onb   = (const float*)d_in[29];
  const float* outw  = (const float*)d_in[30];
  float* ws  = (float*)d_ws;
  float* out = (float*)d_out;

  float* rn   = ws + o_rn;
  float* sn   = ws + o_sn;
  float* pre  = ws + o_pre;
  float* qkv  = ws + o_qkv;
  float* inv  = ws + o_inv;
  float* attn = ws + o_attn;
  float* aout = ws + o_aout;
  float* r    = ws + o_r;
  float* ln2  = ws + o_ln2;
  float* xpre = ws + o_xpre;
  float* xd   = ws + o_xd;
  float* r2   = ws + o_r2;
  float* xxz  = ws + o_xxz;
  float* xcv  = ws + o_xcv;
  float* xdbl = ws + o_xdbl;
  float* yc   = ws + o_yc;
  float* sso  = ws + o_sso;
  float* x2t  = ws + o_x2t;
  float* hend = ws + o_r2;     // scan temp: aliases dead r2
  float* sdt  = ws + o_ln2;    // scan temp: aliases dead ln2

  // attention branch
  k_upln   <<<Bn*L, 64, 0, stream>>>(R, S, c1w, c1b, n1w, n1b, rn, sn);
  k_qkvproj<<<Bn*L, 192, 0, stream>>>(rn, sn, qw, kvw, pre);
  k_dwqkv  <<<Bn*L, 192, 0, stream>>>(pre, qdw, kvdw, qkv);
  k_rownorm<<<Bn*128, 256, 0, stream>>>(qkv, inv);
  k_gram   <<<Bn*2, 1024, 0, stream>>>(qkv, attn);
  k_softmax<<<1, 256, 0, stream>>>(attn, inv, temp);
  k_attnout<<<Bn*2*64, 256, 0, stream>>>(attn, qkv, aout);
  k_projln <<<Bn*L, 64, 0, stream>>>(aout, pjw, R, n2w, n2b, r, ln2);
  // IEL branch
  k_gemm<0,128><<<128*3, 256, 0, stream>>>(ln2, pinw, xpre, nullptr, nullptr, nullptr,
                                           DIN, 64, 64, DIN, 3);
  k_dwx    <<<Bn*L, 384, 0, stream>>>(xpre, dww, ln1w, ln1b, xd, r2);
  // SS2D
  k_gemm<0,128><<<128*6, 256, 0, stream>>>(r2, inw, xxz, nullptr, nullptr, nullptr,
                                           680, HID, HID, 680, 6);
  k_dwss   <<<Bn*L, 384, 0, stream>>>(xxz, scw, scb, xcv);
  k_gemm<1,64><<<16*32, 256, 0, stream>>>(xcv, xpw, xdbl, nullptr, nullptr, nullptr,
                                          XD, DIN, DIN, XDP, 1);
  hipMemsetAsync(yc, 0, (size_t)Bn*L*DIN*sizeof(float), stream);
  k_scan1  <<<16*6*NCH, 64, 0, stream>>>(xcv, xdbl, dtw, dtb, Alog, Dss, yc, hend, sdt);
  k_scomb  <<<16*6, 64, 0, stream>>>(Alog, hend, sdt);
  k_scan2  <<<16*6*(NCH-1), 64, 0, stream>>>(xdbl, dtw, dtb, Alog, hend, yc);
  k_x2t    <<<Bn*L, 192, 0, stream>>>(xd, dw2w, x2t);
  k_yln    <<<Bn*L, 256, 0, stream>>>(yc, xxz, onw, onb);
  k_gemm<0,128><<<128*2, 256, 0, stream>>>(yc, outw, sso, nullptr, nullptr, nullptr,
                                           HID, DIN, DIN, HID, 2);
  k_gemm<2,64><<<128, 256, 0, stream>>>(sso, poutw, out, xd, x2t, r,
                                        64, HID, HID, 64, 1);
}